// Round 1
// 239.478 us; speedup vs baseline: 1.0740x; 1.0740x over previous
//
#include <hip/hip_runtime.h>
#include <hip/hip_bf16.h>
#include <math.h>

#define B_SZ 2
#define L_SZ 1024
#define DM 1024
#define DI 2048
#define NS 16
#define DTR 64
#define NCHUNK 16
#define CLEN 64
#define XDLD 128  // padded x_dbl leading dim
#define KSPLIT 8

typedef unsigned short ushortT;
typedef __attribute__((ext_vector_type(8))) short short8;
typedef __attribute__((ext_vector_type(4))) float floatx4;

__device__ __forceinline__ ushortT f2bf(float f) {
  unsigned u = __float_as_uint(f);
  unsigned r = (u + 0x7fff + ((u >> 16) & 1)) >> 16;
  return (ushortT)r;
}

__device__ __forceinline__ float bf2f(ushortT v) {
  return __uint_as_float((unsigned)v << 16);
}

__device__ __forceinline__ void gl2lds16(const void* g, void* l) {
  __builtin_amdgcn_global_load_lds(
      (const __attribute__((address_space(1))) unsigned int*)g,
      (__attribute__((address_space(3))) unsigned int*)l, 16, 0, 0);
}

// Scan-state stash lives in the dead strided region of xz: floats [1024,2048)
// of each 4096-float row. i in [0, 2M): aprod at i, sfin at i + 1M.
__device__ __forceinline__ unsigned stash_addr(unsigned i) {
  return (i >> 10) * 4096 + 1024 + (i & 1023);
}

// ---------------- f32 -> bf16 convert (4 elems/thread) ----------------
__global__ __launch_bounds__(256) void cvt_bf16(const float* __restrict__ src,
                                                ushortT* __restrict__ dst) {
  const int i = blockIdx.x * 256 + threadIdx.x;
  float4 v = ((const float4*)src)[i];
  unsigned lo = (unsigned)f2bf(v.x) | ((unsigned)f2bf(v.y) << 16);
  unsigned hi = (unsigned)f2bf(v.z) | ((unsigned)f2bf(v.w) << 16);
  ((uint2*)dst)[i] = make_uint2(lo, hi);
}

// ---------------- f32 [R][C] -> bf16 [C][R] transpose ----------------
__global__ __launch_bounds__(256) void transpose_bf16(
    const float* __restrict__ src, ushortT* __restrict__ dst, int R, int C) {
  __shared__ float t[32][33];
  const int bx = blockIdx.x * 32;  // col base
  const int by = blockIdx.y * 32;  // row base
  const int tx = threadIdx.x, ty = threadIdx.y;  // (32,8)
#pragma unroll
  for (int j = 0; j < 4; ++j)
    t[ty + j * 8][tx] = src[(size_t)(by + ty + j * 8) * C + bx + tx];
  __syncthreads();
#pragma unroll
  for (int j = 0; j < 4; ++j)
    dst[(size_t)(bx + ty + j * 8) * R + by + tx] = f2bf(t[tx][ty + j * 8]);
}

// ---------------- Wx (2048x96) -> WxT bf16 (128x2048), rows 96..127 zero ----------------
__global__ __launch_bounds__(256) void wx_pad_t(const float* __restrict__ Wx,
                                                ushortT* __restrict__ WxT) {
  const int k = blockIdx.x * 256 + threadIdx.x;  // 0..2047
  const int n = blockIdx.y;                      // 0..127
  WxT[(size_t)n * DI + k] = (n < 96) ? f2bf(Wx[(size_t)k * 96 + n]) : (ushortT)0;
}

// ---------------- GEMM1: 128x128 tile, BK=64, 4 waves, 512 blocks (2/CU) ----------------
// 32 MFMA/wave per barrier; 16 K-iters; LDS 32 KB.
__global__ __launch_bounds__(256) void gemm1_big(
    const ushortT* __restrict__ A, int lda,
    const ushortT* __restrict__ BT, int ldb,
    float* __restrict__ C, int ldc, int K) {
  __shared__ __align__(16) char smem[128 * 128 + 128 * 128];  // A 16KB | B 16KB
  char* As = smem;
  char* Bs = smem + 128 * 128;
  const int tid = threadIdx.x;
  const int lane = tid & 63;
  const int quad = lane >> 4;
  const int l16 = lane & 15;
  const int wid = tid >> 6;
  const int wm = wid & 1;
  const int wn = wid >> 1;
  const int m0 = blockIdx.y * 128;
  const int n0 = blockIdx.x * 128;

  floatx4 acc[4][4] = {};

  for (int k0 = 0; k0 < K; k0 += 64) {
    for (int i = tid; i < 128 * 8; i += 256) {
      const int r = i >> 3, c = i & 7;
      const int cg = c ^ (r & 7);
      gl2lds16(A + (size_t)(m0 + r) * lda + k0 + cg * 8, As + (i - lane) * 16);
    }
    for (int i = tid; i < 128 * 8; i += 256) {
      const int r = i >> 3, c = i & 7;
      const int cg = c ^ (r & 7);
      gl2lds16(BT + (size_t)(n0 + r) * ldb + k0 + cg * 8, Bs + (i - lane) * 16);
    }
    __syncthreads();

    short8 afr[4][2], bfr[4][2];
#pragma unroll
    for (int i = 0; i < 4; ++i) {
      const int r = wm * 64 + i * 16 + l16;
#pragma unroll
      for (int s = 0; s < 2; ++s)
        afr[i][s] = *(const short8*)(As + r * 128 + (((s * 4 + quad) ^ (r & 7)) * 16));
    }
#pragma unroll
    for (int j = 0; j < 4; ++j) {
      const int r = wn * 64 + j * 16 + l16;
#pragma unroll
      for (int s = 0; s < 2; ++s)
        bfr[j][s] = *(const short8*)(Bs + r * 128 + (((s * 4 + quad) ^ (r & 7)) * 16));
    }
#pragma unroll
    for (int s = 0; s < 2; ++s)
#pragma unroll
      for (int i = 0; i < 4; ++i)
#pragma unroll
        for (int j = 0; j < 4; ++j)
          acc[i][j] = __builtin_amdgcn_mfma_f32_16x16x32_bf16(afr[i][s], bfr[j][s],
                                                              acc[i][j], 0, 0, 0);
    __syncthreads();
  }
#pragma unroll
  for (int i = 0; i < 4; ++i)
#pragma unroll
    for (int j = 0; j < 4; ++j)
#pragma unroll
      for (int r = 0; r < 4; ++r) {
        const int m = m0 + wm * 64 + i * 16 + quad * 4 + r;
        const int n = n0 + wn * 64 + j * 16 + l16;
        C[(size_t)m * ldc + n] = acc[i][j][r];
      }
}

// ---------------- GEMM4: 64x64 tile, BK=64, split-K=2, 1024 blocks ----------------
__global__ __launch_bounds__(128) void gemm_out_split(
    const ushortT* __restrict__ A, int lda,
    const ushortT* __restrict__ BT, int ldb,
    float* __restrict__ part) {
  __shared__ __align__(16) char smem[64 * 128 + 64 * 128];  // 8KB + 8KB
  char* As = smem;
  char* Bs = smem + 64 * 128;
  const int tid = threadIdx.x;
  const int lane = tid & 63;
  const int quad = lane >> 4;
  const int l16 = lane & 15;
  const int wm = tid >> 6;  // 0/1: 32-row half
  const int m0 = blockIdx.y * 64;
  const int n0 = blockIdx.x * 64;
  const int kb = blockIdx.z * (DI / 2);

  floatx4 acc[2][4] = {};

  for (int k0 = kb; k0 < kb + DI / 2; k0 += 64) {
    for (int i = tid; i < 64 * 8; i += 128) {
      const int r = i >> 3, c = i & 7;
      const int cg = c ^ (r & 7);
      gl2lds16(A + (size_t)(m0 + r) * lda + k0 + cg * 8, As + (i - lane) * 16);
    }
    for (int i = tid; i < 64 * 8; i += 128) {
      const int r = i >> 3, c = i & 7;
      const int cg = c ^ (r & 7);
      gl2lds16(BT + (size_t)(n0 + r) * ldb + k0 + cg * 8, Bs + (i - lane) * 16);
    }
    __syncthreads();

    short8 afr[2][2], bfr[4][2];
#pragma unroll
    for (int i = 0; i < 2; ++i) {
      const int m = wm * 32 + i * 16 + l16;
#pragma unroll
      for (int s = 0; s < 2; ++s)
        afr[i][s] = *(const short8*)(As + m * 128 + (((s * 4 + quad) ^ (m & 7)) * 16));
    }
#pragma unroll
    for (int j = 0; j < 4; ++j) {
      const int n = j * 16 + l16;
#pragma unroll
      for (int s = 0; s < 2; ++s)
        bfr[j][s] = *(const short8*)(Bs + n * 128 + (((s * 4 + quad) ^ (n & 7)) * 16));
    }
#pragma unroll
    for (int s = 0; s < 2; ++s)
#pragma unroll
      for (int i = 0; i < 2; ++i)
#pragma unroll
        for (int j = 0; j < 4; ++j)
          acc[i][j] = __builtin_amdgcn_mfma_f32_16x16x32_bf16(afr[i][s], bfr[j][s],
                                                              acc[i][j], 0, 0, 0);
    __syncthreads();
  }
  float* out = part + (size_t)blockIdx.z * (B_SZ * L_SZ * DM);
#pragma unroll
  for (int i = 0; i < 2; ++i)
#pragma unroll
    for (int j = 0; j < 4; ++j)
#pragma unroll
      for (int r = 0; r < 4; ++r) {
        const int m = m0 + wm * 32 + i * 16 + quad * 4 + r;
        const int n = n0 + j * 16 + l16;
        out[(size_t)m * DM + n] = acc[i][j][r];
      }
}

// ------------- out = part0 + part1 (float4 per thread) -------------
__global__ __launch_bounds__(256) void reduce_out(const float* __restrict__ part,
                                                  float* __restrict__ out) {
  const int i = blockIdx.x * 256 + threadIdx.x;
  const float4 a = ((const float4*)part)[i];
  const float4 b = ((const float4*)part)[(size_t)(B_SZ * L_SZ * DM / 4) + i];
  ((float4*)out)[i] = make_float4(a.x + b.x, a.y + b.y, a.z + b.z, a.w + b.w);
}

// ------------- x_dbl partials: xc(bf16) @ Wx (padded N=128), K-split via MFMA -------------
__global__ __launch_bounds__(256) void gemm_xdbl_mfma(
    const ushortT* __restrict__ xcb, const ushortT* __restrict__ WxT,
    float* __restrict__ part) {
  __shared__ __align__(16) char smem[64 * 64 + 128 * 64];
  char* As = smem;             // [64 r][64 B bf16]
  char* Bs = smem + 64 * 64;   // [128 r][64 B bf16]
  const int tid = threadIdx.x;
  const int lane = tid & 63;
  const int quad = lane >> 4;
  const int l16 = lane & 15;
  const int wid = tid >> 6;
  const int wm = wid & 1;
  const int wn = wid >> 1;
  const int m0 = blockIdx.x * 64;
  const int kbase = blockIdx.y * (DI / KSPLIT);

  floatx4 acc[2][4] = {};

  for (int kk = 0; kk < DI / KSPLIT; kk += 32) {
    const int k0 = kbase + kk;
    for (int i = tid; i < 64 * 4; i += 256) {
      const int r = i >> 2, c = i & 3;
      const int cg = c ^ (r & 3);
      gl2lds16(xcb + (size_t)(m0 + r) * DI + k0 + cg * 8, As + (i - lane) * 16);
    }
    for (int i = tid; i < 128 * 4; i += 256) {
      const int r = i >> 2, c = i & 3;
      const int cg = c ^ (r & 3);
      gl2lds16(WxT + (size_t)r * DI + k0 + cg * 8, Bs + (i - lane) * 16);
    }
    __syncthreads();

    short8 afr[2], bfr[4];
#pragma unroll
    for (int i = 0; i < 2; ++i) {
      const int m = wm * 32 + i * 16 + l16;
      afr[i] = *(const short8*)(As + m * 64 + ((quad ^ (m & 3)) * 16));
    }
#pragma unroll
    for (int j = 0; j < 4; ++j) {
      const int n = wn * 64 + j * 16 + l16;
      bfr[j] = *(const short8*)(Bs + n * 64 + ((quad ^ (n & 3)) * 16));
    }
#pragma unroll
    for (int i = 0; i < 2; ++i)
#pragma unroll
      for (int j = 0; j < 4; ++j)
        acc[i][j] = __builtin_amdgcn_mfma_f32_16x16x32_bf16(afr[i], bfr[j],
                                                            acc[i][j], 0, 0, 0);
    __syncthreads();
  }
  float* out = part + (size_t)blockIdx.y * (B_SZ * L_SZ * XDLD);
#pragma unroll
  for (int i = 0; i < 2; ++i)
#pragma unroll
    for (int j = 0; j < 4; ++j)
#pragma unroll
      for (int r = 0; r < 4; ++r) {
        const int m = m0 + wm * 32 + i * 16 + quad * 4 + r;
        const int n = wn * 64 + j * 16 + l16;
        out[(size_t)m * XDLD + n] = acc[i][j][r];
      }
}

// ------------- xdbl = sum of KSPLIT partials; also emit dt cols 0..63 as bf16 -------------
__global__ __launch_bounds__(256) void xdbl_reduce(const float* __restrict__ part,
                                                   float* __restrict__ xdbl,
                                                   ushortT* __restrict__ dtb) {
  const int i = blockIdx.x * 256 + threadIdx.x;  // float4 index, [0, 65536)
  float4 a = ((const float4*)part)[i];
#pragma unroll
  for (int s = 1; s < KSPLIT; ++s) {
    const float4 b = ((const float4*)part)[(size_t)s * (B_SZ * L_SZ * XDLD / 4) + i];
    a.x += b.x; a.y += b.y; a.z += b.z; a.w += b.w;
  }
  ((float4*)xdbl)[i] = a;
  // dt = xdbl[:, 0:64] -> compact bf16 [2048][64] for gemm_delta's A operand
  const int row = i >> 5;           // 32 float4 per 128-col row
  const int c4 = (i & 31) * 4;      // column of this float4
  if (c4 < DTR) {
    const unsigned lo = (unsigned)f2bf(a.x) | ((unsigned)f2bf(a.y) << 16);
    const unsigned hi = (unsigned)f2bf(a.z) | ((unsigned)f2bf(a.w) << 16);
    ((uint2*)dtb)[row * (DTR / 4) + (c4 >> 2)] = make_uint2(lo, hi);
  }
}

// ------------- causal depthwise conv (k=4) + silu -> xc bf16 (8-row tiles) -------------
__global__ __launch_bounds__(256) void conv_silu(
    const float* __restrict__ xz, const float* __restrict__ kern,
    const float* __restrict__ bias, ushortT* __restrict__ xcb) {
  const int d = blockIdx.y * 256 + threadIdx.x;
  const int b = blockIdx.x >> 7;           // 128 8-row chunks per batch
  const int l0 = (blockIdx.x & 127) * 8;
  const int row0 = b * L_SZ + l0;
  const float k0v = kern[0 * DI + d], k1v = kern[1 * DI + d];
  const float k2v = kern[2 * DI + d], k3v = kern[3 * DI + d];
  float xv[11];
#pragma unroll
  for (int i = 0; i < 11; ++i) {
    const int l = l0 - 3 + i;
    xv[i] = (l >= 0) ? xz[((size_t)(b * L_SZ + l)) * 4096 + d] : 0.f;
  }
  const float bs = bias[d];
#pragma unroll
  for (int j = 0; j < 8; ++j) {
    float a = bs;
    a = fmaf(xv[j], k0v, a);
    a = fmaf(xv[j + 1], k1v, a);
    a = fmaf(xv[j + 2], k2v, a);
    a = fmaf(xv[j + 3], k3v, a);
    xcb[(size_t)(row0 + j) * DI + d] = f2bf(a / (1.f + __expf(-a)));
  }
}

// ------------- delta = softplus(dt @ Wdt + dt_bias), pure bf16, single K=64 stage -------------
// 64x64 tile, 1024 blocks (4/CU), one barrier pair, fast inline softplus (no log1pf).
__global__ __launch_bounds__(256) void gemm_delta_mfma(
    const ushortT* __restrict__ dtb, const ushortT* __restrict__ WdtT,
    const float* __restrict__ dt_bias, float* __restrict__ delta) {
  __shared__ __align__(16) char smem[64 * 128 + 64 * 128];  // A 8KB | B 8KB
  char* As = smem;
  char* Bs = smem + 64 * 128;
  const int tid = threadIdx.x;
  const int lane = tid & 63;
  const int quad = lane >> 4;
  const int l16 = lane & 15;
  const int wid = tid >> 6;
  const int wm = wid & 1;
  const int wn = wid >> 1;
  const int m0 = blockIdx.x * 64;
  const int n0 = blockIdx.y * 64;

  // Stage A (dt bf16 [64][64]) and B (WdtT [64][64]) — full K=64, one shot.
  for (int i = tid; i < 64 * 8; i += 256) {
    const int r = i >> 3, c = i & 7;
    const int cg = c ^ (r & 7);
    gl2lds16(dtb + (size_t)(m0 + r) * DTR + cg * 8, As + (i - lane) * 16);
  }
  for (int i = tid; i < 64 * 8; i += 256) {
    const int r = i >> 3, c = i & 7;
    const int cg = c ^ (r & 7);
    gl2lds16(WdtT + (size_t)(n0 + r) * DTR + cg * 8, Bs + (i - lane) * 16);
  }
  __syncthreads();

  floatx4 acc[2][2] = {};
  short8 afr[2][2], bfr[2][2];
#pragma unroll
  for (int i = 0; i < 2; ++i) {
    const int m = wm * 32 + i * 16 + l16;
#pragma unroll
    for (int s = 0; s < 2; ++s)
      afr[i][s] = *(const short8*)(As + m * 128 + (((s * 4 + quad) ^ (m & 7)) * 16));
  }
#pragma unroll
  for (int j = 0; j < 2; ++j) {
    const int n = wn * 32 + j * 16 + l16;
#pragma unroll
    for (int s = 0; s < 2; ++s)
      bfr[j][s] = *(const short8*)(Bs + n * 128 + (((s * 4 + quad) ^ (n & 7)) * 16));
  }
#pragma unroll
  for (int s = 0; s < 2; ++s)
#pragma unroll
    for (int i = 0; i < 2; ++i)
#pragma unroll
      for (int j = 0; j < 2; ++j)
        acc[i][j] = __builtin_amdgcn_mfma_f32_16x16x32_bf16(afr[i][s], bfr[j][s],
                                                            acc[i][j], 0, 0, 0);

#pragma unroll
  for (int i = 0; i < 2; ++i)
#pragma unroll
    for (int j = 0; j < 2; ++j) {
      const int n = n0 + wn * 32 + j * 16 + l16;
      const float bias = dt_bias[n];
#pragma unroll
      for (int r = 0; r < 4; ++r) {
        const int m = m0 + wm * 32 + i * 16 + quad * 4 + r;
        const float a = acc[i][j][r] + bias;
        // softplus: a>20 guard covers overflow; expf underflow -> log(1)=0 is exact.
        delta[(size_t)m * DI + n] = (a > 20.f) ? a : __logf(1.f + __expf(a));
      }
    }
}

// ------------- scan phase 1: per-chunk transition -------------
__global__ __launch_bounds__(256) void scan_phase1(
    const float* __restrict__ delta, const ushortT* __restrict__ xcb,
    const float* __restrict__ xdbl, const float* __restrict__ A_log,
    float* __restrict__ xz) {
  const int bx = blockIdx.x;
  const int b = bx >> 9;
  const int c = (bx >> 5) & 15;
  const int dt = bx & 31;
  const int tid = threadIdx.x;
  const int dl = tid >> 2, nq = tid & 3;
  const int d = dt * 64 + dl;
  const int row0 = b * L_SZ + c * CLEN;

  __shared__ float Bsh[CLEN][16];
  for (int i = tid; i < CLEN * 16; i += 256)
    Bsh[i >> 4][i & 15] = xdbl[(size_t)(row0 + (i >> 4)) * XDLD + 64 + (i & 15)];

  float Av[4];
#pragma unroll
  for (int j = 0; j < 4; ++j) Av[j] = -__expf(A_log[d * 16 + nq * 4 + j]);
  float x[4] = {}, P[4] = {1.f, 1.f, 1.f, 1.f};
  __syncthreads();

  const float* dp = delta + (size_t)row0 * DI + d;
  const ushortT* up = xcb + (size_t)row0 * DI + d;
  float dB[4], uB[4];
#pragma unroll
  for (int j = 0; j < 4; ++j) {
    dB[j] = dp[(size_t)j * DI];
    uB[j] = bf2f(up[(size_t)j * DI]);
  }
  for (int l0 = 0; l0 < CLEN; l0 += 4) {
    float dN[4] = {}, uN[4] = {};
    if (l0 + 4 < CLEN) {
#pragma unroll
      for (int j = 0; j < 4; ++j) {
        dN[j] = dp[(size_t)(l0 + 4 + j) * DI];
        uN[j] = bf2f(up[(size_t)(l0 + 4 + j) * DI]);
      }
    }
#pragma unroll
    for (int jj = 0; jj < 4; ++jj) {
      const float dlt = dB[jj];
      const float t = dlt * uB[jj];
      const float* bb = &Bsh[l0 + jj][nq * 4];
#pragma unroll
      for (int n = 0; n < 4; ++n) {
        const float dA = __expf(dlt * Av[n]);
        P[n] *= dA;
        x[n] = fmaf(dA, x[n], t * bb[n]);
      }
    }
#pragma unroll
    for (int j = 0; j < 4; ++j) { dB[j] = dN[j]; uB[j] = uN[j]; }
  }
  const unsigned sb = ((unsigned)((b * NCHUNK + c) * DI + d)) * 16 + nq * 4;
  *(float4*)&xz[stash_addr(sb)] = make_float4(P[0], P[1], P[2], P[3]);
  *(float4*)&xz[stash_addr((1u << 20) + sb)] = make_float4(x[0], x[1], x[2], x[3]);
}

// ------------- scan phase 2: sequential chunk combine -------------
__global__ __launch_bounds__(256) void scan_phase2(float* __restrict__ xz) {
  const int t = blockIdx.x * 256 + threadIdx.x;
  const int b = t >> 15;
  const int rem = t & 32767;
  float x = 0.f;
#pragma unroll
  for (int c = 0; c < NCHUNK; ++c) {
    const unsigned i = ((unsigned)(b * NCHUNK + c) << 15) + rem;
    float* Pr = &xz[stash_addr(i)];
    float* Sr = &xz[stash_addr((1u << 20) + i)];
    const float P = *Pr, S = *Sr;
    *Sr = x;
    x = fmaf(P, x, S);
  }
}

// ------------- scan phase 3: rescan w/ init + y + skip + gate -> bf16 y -------------
__global__ __launch_bounds__(256) void scan_phase3(
    const float* __restrict__ delta, const ushortT* __restrict__ xcb,
    const float* __restrict__ xdbl, const float* __restrict__ A_log,
    const float* __restrict__ Dskip, float* __restrict__ xz) {
  const int bx = blockIdx.x;
  const int b = bx >> 9;
  const int c = (bx >> 5) & 15;
  const int dt = bx & 31;
  const int tid = threadIdx.x;
  const int dl = tid >> 2, nq = tid & 3;
  const int d = dt * 64 + dl;
  const int row0 = b * L_SZ + c * CLEN;

  __shared__ float Bsh[CLEN][16], Csh[CLEN][16];
  for (int i = tid; i < CLEN * 32; i += 256) {
    const int r = i >> 5, q = i & 31;
    const float v = xdbl[(size_t)(row0 + r) * XDLD + 64 + q];
    if (q < 16) Bsh[r][q] = v; else Csh[r][q - 16] = v;
  }

  float Av[4];
#pragma unroll
  for (int j = 0; j < 4; ++j) Av[j] = -__expf(A_log[d * 16 + nq * 4 + j]);
  const float Dsk = Dskip[d];
  const unsigned sb = ((unsigned)((b * NCHUNK + c) * DI + d)) * 16 + nq * 4;
  const float4 xi = *(const float4*)&xz[stash_addr((1u << 20) + sb)];
  float x[4] = {xi.x, xi.y, xi.z, xi.w};
  __syncthreads();

  const float* dp = delta + (size_t)row0 * DI + d;
  const ushortT* up = xcb + (size_t)row0 * DI + d;
  const float* zp = xz + (size_t)row0 * 4096 + DI + d;
  ushortT* yb = (ushortT*)xz;

  float dB[4], uB[4], zB[4];
#pragma unroll
  for (int j = 0; j < 4; ++j) {
    dB[j] = dp[(size_t)j * DI];
    uB[j] = bf2f(up[(size_t)j * DI]);
    zB[j] = zp[(size_t)j * 4096];
  }
  for (int l0 = 0; l0 < CLEN; l0 += 4) {
    float dN[4] = {}, uN[4] = {}, zN[4] = {};
    if (l0 + 4 < CLEN) {
#pragma unroll
      for (int j = 0; j < 4; ++j) {
        dN[j] = dp[(size_t)(l0 + 4 + j) * DI];
        uN[j] = bf2f(up[(size_t)(l0 + 4 + j) * DI]);
        zN[j] = zp[(size_t)(l0 + 4 + j) * 4096];
      }
    }
#pragma unroll
    for (int jj = 0; jj < 4; ++jj) {
      const float dlt = dB[jj];
      const float u = uB[jj];
      const float t = dlt * u;
      const float* bb = &Bsh[l0 + jj][nq * 4];
      const float* cc = &Csh[l0 + jj][nq * 4];
      float y = 0.f;
#pragma unroll
      for (int n = 0; n < 4; ++n) {
        const float dA = __expf(dlt * Av[n]);
        x[n] = fmaf(dA, x[n], t * bb[n]);
        y = fmaf(x[n], cc[n], y);
      }
      y += __shfl_xor(y, 1);
      y += __shfl_xor(y, 2);
      if (nq == 0) {
        const float z = zB[jj];
        const float g = (y + u * Dsk) * (z / (1.f + __expf(-z)));
        yb[(size_t)(row0 + l0 + jj) * 8192 + d] = f2bf(g);
      }
    }
#pragma unroll
    for (int j = 0; j < 4; ++j) { dB[j] = dN[j]; uB[j] = uN[j]; zB[j] = zN[j]; }
  }
}

extern "C" void kernel_launch(void* const* d_in, const int* in_sizes, int n_in,
                              void* d_out, int out_size, void* d_ws, size_t ws_size,
                              hipStream_t stream) {
  const float* hidden  = (const float*)d_in[0];
  const float* Win     = (const float*)d_in[1];
  const float* Wx      = (const float*)d_in[2];
  const float* Wdt     = (const float*)d_in[3];
  const float* dt_bias = (const float*)d_in[4];
  const float* Wout    = (const float*)d_in[5];
  const float* dwk     = (const float*)d_in[6];
  const float* dwb     = (const float*)d_in[7];
  const float* A_log   = (const float*)d_in[8];
  const float* Dskip   = (const float*)d_in[9];

  // ws (64 MB): xz 32MB | shared16 (WinT -> xdbl partials -> delta -> WoutT) 16MB
  //             | xc region 16MB: bf16 xc [0,8M); GEMM4 split-K partials reuse all 16MB
  // xz per-row float layout: [0,1024) y-bf16 | [1024,2048) scan stash | [2048,4096) z
  char* ws = (char*)d_ws;
  float* xz       = (float*)ws;
  float* shared16 = (float*)(ws + (32u << 20));
  float* xcreg    = (float*)(ws + (48u << 20));
  ushortT* xcb    = (ushortT*)xcreg;
  // d_out (8 MB) scratch: hidb [0,4M) (dead after GEMM1); xdbl128 [4M,5M);
  //                       WxT [5M,5.5M); WdtT [5.5M,5.75M); dtb [5.75M,6M)
  char* dob = (char*)d_out;
  ushortT* hidb = (ushortT*)dob;
  float* xdbl   = (float*)(dob + (4u << 20));
  ushortT* WxT  = (ushortT*)(dob + (5u << 20));
  ushortT* WdtT = (ushortT*)(dob + (5u << 20) + (512u << 10));
  ushortT* dtb  = (ushortT*)(dob + (5u << 20) + (768u << 10));

  // 1. hidden -> bf16
  cvt_bf16<<<dim3(B_SZ * L_SZ * DM / 1024), 256, 0, stream>>>(hidden, hidb);
  // 2. Win (1024x4096) -> WinT bf16 (4096x1024) in shared16
  transpose_bf16<<<dim3(4096 / 32, 1024 / 32), dim3(32, 8), 0, stream>>>(
      Win, (ushortT*)shared16, DM, 2 * DI);
  // 3. Wx -> WxT bf16 padded (128 x 2048); Wdt (64x2048) -> WdtT bf16 (2048x64)
  wx_pad_t<<<dim3(DI / 256, 128), 256, 0, stream>>>(Wx, WxT);
  transpose_bf16<<<dim3(DI / 32, DTR / 32), dim3(32, 8), 0, stream>>>(
      Wdt, WdtT, DTR, DI);
  // 4. GEMM1: xz = hidden @ Win  (M=2048, N=4096, K=1024); 128x128, BK=64, 512 blocks
  gemm1_big<<<dim3(4096 / 128, 2048 / 128), 256, 0, stream>>>(
      hidb, DM, (ushortT*)shared16, DM, xz, 2 * DI, DM);
  // 5. depthwise conv + silu -> xc bf16 (8-row tiles)
  conv_silu<<<dim3(B_SZ * L_SZ / 8, DI / 256), 256, 0, stream>>>(xz, dwk, dwb, xcb);
  // 6. x_dbl partials (K-split 8) -> shared16 [0,8M) (WinT dead), then reduce (+dt bf16)
  gemm_xdbl_mfma<<<dim3(B_SZ * L_SZ / 64, KSPLIT), 256, 0, stream>>>(
      xcb, WxT, shared16);
  xdbl_reduce<<<dim3(B_SZ * L_SZ * XDLD / 1024), 256, 0, stream>>>(shared16, xdbl, dtb);
  // 7. delta = softplus(dt @ Wdt + bias): pure-bf16 MFMA, single K=64 stage, 1024 blocks
  gemm_delta_mfma<<<dim3(B_SZ * L_SZ / 64, DI / 64), 256, 0, stream>>>(
      dtb, WdtT, dt_bias, shared16);
  // 8-10. chunked selective scan (states in xz stash); y (gated, bf16) -> xz
  scan_phase1<<<dim3(B_SZ * NCHUNK * (DI / 64)), 256, 0, stream>>>(
      shared16, xcb, xdbl, A_log, xz);
  scan_phase2<<<dim3(B_SZ * DI * NS / 256), 256, 0, stream>>>(xz);
  scan_phase3<<<dim3(B_SZ * NCHUNK * (DI / 64)), 256, 0, stream>>>(
      shared16, xcb, xdbl, A_log, Dskip, xz);
  // 11. Wout (2048x1024) -> WoutT bf16 (1024x2048) in shared16 (delta dead)
  transpose_bf16<<<dim3(1024 / 32, 2048 / 32), dim3(32, 8), 0, stream>>>(
      Wout, (ushortT*)shared16, DI, DM);
  // 12. GEMM4 split-K=2: partials -> xc region (dead after scan), then reduce -> d_out
  gemm_out_split<<<dim3(1024 / 64, 2048 / 64, 2), 128, 0, stream>>>(
      (ushortT*)xz, 4 * DI, (ushortT*)shared16, DI, xcreg);
  reduce_out<<<dim3(B_SZ * L_SZ * DM / 1024), 256, 0, stream>>>(xcreg, (float*)d_out);
}

// Round 2
// 239.364 us; speedup vs baseline: 1.0745x; 1.0005x over previous
//
#include <hip/hip_runtime.h>
#include <hip/hip_bf16.h>
#include <math.h>

#define B_SZ 2
#define L_SZ 1024
#define DM 1024
#define DI 2048
#define NS 16
#define DTR 64
#define NCHUNK 16
#define CLEN 64
#define XDLD 128  // padded x_dbl leading dim
#define KSPLIT 16

typedef unsigned short ushortT;
typedef __attribute__((ext_vector_type(8))) short short8;
typedef __attribute__((ext_vector_type(4))) float floatx4;

__device__ __forceinline__ ushortT f2bf(float f) {
  unsigned u = __float_as_uint(f);
  unsigned r = (u + 0x7fff + ((u >> 16) & 1)) >> 16;
  return (ushortT)r;
}

__device__ __forceinline__ float bf2f(ushortT v) {
  return __uint_as_float((unsigned)v << 16);
}

__device__ __forceinline__ void gl2lds16(const void* g, void* l) {
  __builtin_amdgcn_global_load_lds(
      (const __attribute__((address_space(1))) unsigned int*)g,
      (__attribute__((address_space(3))) unsigned int*)l, 16, 0, 0);
}

// Scan-state stash lives in the dead strided region of xz: floats [1024,2048)
// of each 4096-float row. i in [0, 2M): aprod at i, sfin at i + 1M.
__device__ __forceinline__ unsigned stash_addr(unsigned i) {
  return (i >> 10) * 4096 + 1024 + (i & 1023);
}

// ---------------- f32 -> bf16 convert (4 elems/thread) ----------------
__global__ __launch_bounds__(256) void cvt_bf16(const float* __restrict__ src,
                                                ushortT* __restrict__ dst) {
  const int i = blockIdx.x * 256 + threadIdx.x;
  float4 v = ((const float4*)src)[i];
  unsigned lo = (unsigned)f2bf(v.x) | ((unsigned)f2bf(v.y) << 16);
  unsigned hi = (unsigned)f2bf(v.z) | ((unsigned)f2bf(v.w) << 16);
  ((uint2*)dst)[i] = make_uint2(lo, hi);
}

// ---------------- f32 [R][C] -> bf16 [C][R] transpose ----------------
__global__ __launch_bounds__(256) void transpose_bf16(
    const float* __restrict__ src, ushortT* __restrict__ dst, int R, int C) {
  __shared__ float t[32][33];
  const int bx = blockIdx.x * 32;  // col base
  const int by = blockIdx.y * 32;  // row base
  const int tx = threadIdx.x, ty = threadIdx.y;  // (32,8)
#pragma unroll
  for (int j = 0; j < 4; ++j)
    t[ty + j * 8][tx] = src[(size_t)(by + ty + j * 8) * C + bx + tx];
  __syncthreads();
#pragma unroll
  for (int j = 0; j < 4; ++j)
    dst[(size_t)(bx + ty + j * 8) * R + by + tx] = f2bf(t[tx][ty + j * 8]);
}

// ---------------- Wx (2048x96) -> WxT bf16 (128x2048), rows 96..127 zero ----------------
__global__ __launch_bounds__(256) void wx_pad_t(const float* __restrict__ Wx,
                                                ushortT* __restrict__ WxT) {
  const int k = blockIdx.x * 256 + threadIdx.x;  // 0..2047
  const int n = blockIdx.y;                      // 0..127
  WxT[(size_t)n * DI + k] = (n < 96) ? f2bf(Wx[(size_t)k * 96 + n]) : (ushortT)0;
}

// ---------------- GEMM1: 128x128 tile, BK=64, 8 waves (512 thr), 512 blocks ----------------
// wave tile 64x32, acc 4x2; 16 waves/CU (4/SIMD) for latency hiding.
__global__ __launch_bounds__(512) void gemm1_big(
    const ushortT* __restrict__ A, int lda,
    const ushortT* __restrict__ BT, int ldb,
    float* __restrict__ C, int ldc, int K) {
  __shared__ __align__(16) char smem[128 * 128 + 128 * 128];  // A 16KB | B 16KB
  char* As = smem;
  char* Bs = smem + 128 * 128;
  const int tid = threadIdx.x;
  const int lane = tid & 63;
  const int quad = lane >> 4;
  const int l16 = lane & 15;
  const int wid = tid >> 6;
  const int wm = wid & 1;   // 2 m-halves of 64
  const int wn = wid >> 1;  // 4 n-quarters of 32
  const int m0 = blockIdx.y * 128;
  const int n0 = blockIdx.x * 128;

  floatx4 acc[4][2] = {};

  for (int k0 = 0; k0 < K; k0 += 64) {
    for (int i = tid; i < 128 * 8; i += 512) {
      const int r = i >> 3, c = i & 7;
      const int cg = c ^ (r & 7);
      gl2lds16(A + (size_t)(m0 + r) * lda + k0 + cg * 8, As + (i - lane) * 16);
    }
    for (int i = tid; i < 128 * 8; i += 512) {
      const int r = i >> 3, c = i & 7;
      const int cg = c ^ (r & 7);
      gl2lds16(BT + (size_t)(n0 + r) * ldb + k0 + cg * 8, Bs + (i - lane) * 16);
    }
    __syncthreads();

    short8 afr[4][2], bfr[2][2];
#pragma unroll
    for (int i = 0; i < 4; ++i) {
      const int r = wm * 64 + i * 16 + l16;
#pragma unroll
      for (int s = 0; s < 2; ++s)
        afr[i][s] = *(const short8*)(As + r * 128 + (((s * 4 + quad) ^ (r & 7)) * 16));
    }
#pragma unroll
    for (int j = 0; j < 2; ++j) {
      const int r = wn * 32 + j * 16 + l16;
#pragma unroll
      for (int s = 0; s < 2; ++s)
        bfr[j][s] = *(const short8*)(Bs + r * 128 + (((s * 4 + quad) ^ (r & 7)) * 16));
    }
#pragma unroll
    for (int s = 0; s < 2; ++s)
#pragma unroll
      for (int i = 0; i < 4; ++i)
#pragma unroll
        for (int j = 0; j < 2; ++j)
          acc[i][j] = __builtin_amdgcn_mfma_f32_16x16x32_bf16(afr[i][s], bfr[j][s],
                                                              acc[i][j], 0, 0, 0);
    __syncthreads();
  }
#pragma unroll
  for (int i = 0; i < 4; ++i)
#pragma unroll
    for (int j = 0; j < 2; ++j)
#pragma unroll
      for (int r = 0; r < 4; ++r) {
        const int m = m0 + wm * 64 + i * 16 + quad * 4 + r;
        const int n = n0 + wn * 32 + j * 16 + l16;
        C[(size_t)m * ldc + n] = acc[i][j][r];
      }
}

// ---------------- GEMM4: 64x64 tile, BK=64, split-K=2, 4 waves, 1024 blocks ----------------
// wave tile 32x32, acc 2x2; 16 waves/CU.
__global__ __launch_bounds__(256) void gemm_out_split(
    const ushortT* __restrict__ A, int lda,
    const ushortT* __restrict__ BT, int ldb,
    float* __restrict__ part) {
  __shared__ __align__(16) char smem[64 * 128 + 64 * 128];  // 8KB + 8KB
  char* As = smem;
  char* Bs = smem + 64 * 128;
  const int tid = threadIdx.x;
  const int lane = tid & 63;
  const int quad = lane >> 4;
  const int l16 = lane & 15;
  const int wid = tid >> 6;
  const int wm = wid & 1;   // 2 m-halves of 32
  const int wn = wid >> 1;  // 2 n-halves of 32
  const int m0 = blockIdx.y * 64;
  const int n0 = blockIdx.x * 64;
  const int kb = blockIdx.z * (DI / 2);

  floatx4 acc[2][2] = {};

  for (int k0 = kb; k0 < kb + DI / 2; k0 += 64) {
    for (int i = tid; i < 64 * 8; i += 256) {
      const int r = i >> 3, c = i & 7;
      const int cg = c ^ (r & 7);
      gl2lds16(A + (size_t)(m0 + r) * lda + k0 + cg * 8, As + (i - lane) * 16);
    }
    for (int i = tid; i < 64 * 8; i += 256) {
      const int r = i >> 3, c = i & 7;
      const int cg = c ^ (r & 7);
      gl2lds16(BT + (size_t)(n0 + r) * ldb + k0 + cg * 8, Bs + (i - lane) * 16);
    }
    __syncthreads();

    short8 afr[2][2], bfr[2][2];
#pragma unroll
    for (int i = 0; i < 2; ++i) {
      const int m = wm * 32 + i * 16 + l16;
#pragma unroll
      for (int s = 0; s < 2; ++s)
        afr[i][s] = *(const short8*)(As + m * 128 + (((s * 4 + quad) ^ (m & 7)) * 16));
    }
#pragma unroll
    for (int j = 0; j < 2; ++j) {
      const int n = wn * 32 + j * 16 + l16;
#pragma unroll
      for (int s = 0; s < 2; ++s)
        bfr[j][s] = *(const short8*)(Bs + n * 128 + (((s * 4 + quad) ^ (n & 7)) * 16));
    }
#pragma unroll
    for (int s = 0; s < 2; ++s)
#pragma unroll
      for (int i = 0; i < 2; ++i)
#pragma unroll
        for (int j = 0; j < 2; ++j)
          acc[i][j] = __builtin_amdgcn_mfma_f32_16x16x32_bf16(afr[i][s], bfr[j][s],
                                                              acc[i][j], 0, 0, 0);
    __syncthreads();
  }
  float* out = part + (size_t)blockIdx.z * (B_SZ * L_SZ * DM);
#pragma unroll
  for (int i = 0; i < 2; ++i)
#pragma unroll
    for (int j = 0; j < 2; ++j)
#pragma unroll
      for (int r = 0; r < 4; ++r) {
        const int m = m0 + wm * 32 + i * 16 + quad * 4 + r;
        const int n = n0 + wn * 32 + j * 16 + l16;
        out[(size_t)m * DM + n] = acc[i][j][r];
      }
}

// ------------- out = part0 + part1 (float4 per thread) -------------
__global__ __launch_bounds__(256) void reduce_out(const float* __restrict__ part,
                                                  float* __restrict__ out) {
  const int i = blockIdx.x * 256 + threadIdx.x;
  const float4 a = ((const float4*)part)[i];
  const float4 b = ((const float4*)part)[(size_t)(B_SZ * L_SZ * DM / 4) + i];
  ((float4*)out)[i] = make_float4(a.x + b.x, a.y + b.y, a.z + b.z, a.w + b.w);
}

// ------------- x_dbl partials: xc(bf16) @ Wx (padded N=128), K-split via MFMA -------------
__global__ __launch_bounds__(256) void gemm_xdbl_mfma(
    const ushortT* __restrict__ xcb, const ushortT* __restrict__ WxT,
    float* __restrict__ part) {
  __shared__ __align__(16) char smem[64 * 64 + 128 * 64];
  char* As = smem;             // [64 r][64 B bf16]
  char* Bs = smem + 64 * 64;   // [128 r][64 B bf16]
  const int tid = threadIdx.x;
  const int lane = tid & 63;
  const int quad = lane >> 4;
  const int l16 = lane & 15;
  const int wid = tid >> 6;
  const int wm = wid & 1;
  const int wn = wid >> 1;
  const int m0 = blockIdx.x * 64;
  const int kbase = blockIdx.y * (DI / KSPLIT);

  floatx4 acc[2][4] = {};

  for (int kk = 0; kk < DI / KSPLIT; kk += 32) {
    const int k0 = kbase + kk;
    for (int i = tid; i < 64 * 4; i += 256) {
      const int r = i >> 2, c = i & 3;
      const int cg = c ^ (r & 3);
      gl2lds16(xcb + (size_t)(m0 + r) * DI + k0 + cg * 8, As + (i - lane) * 16);
    }
    for (int i = tid; i < 128 * 4; i += 256) {
      const int r = i >> 2, c = i & 3;
      const int cg = c ^ (r & 3);
      gl2lds16(WxT + (size_t)r * DI + k0 + cg * 8, Bs + (i - lane) * 16);
    }
    __syncthreads();

    short8 afr[2], bfr[4];
#pragma unroll
    for (int i = 0; i < 2; ++i) {
      const int m = wm * 32 + i * 16 + l16;
      afr[i] = *(const short8*)(As + m * 64 + ((quad ^ (m & 3)) * 16));
    }
#pragma unroll
    for (int j = 0; j < 4; ++j) {
      const int n = wn * 64 + j * 16 + l16;
      bfr[j] = *(const short8*)(Bs + n * 64 + ((quad ^ (n & 3)) * 16));
    }
#pragma unroll
    for (int i = 0; i < 2; ++i)
#pragma unroll
      for (int j = 0; j < 4; ++j)
        acc[i][j] = __builtin_amdgcn_mfma_f32_16x16x32_bf16(afr[i], bfr[j],
                                                            acc[i][j], 0, 0, 0);
    __syncthreads();
  }
  float* out = part + (size_t)blockIdx.y * (B_SZ * L_SZ * XDLD);
#pragma unroll
  for (int i = 0; i < 2; ++i)
#pragma unroll
    for (int j = 0; j < 4; ++j)
#pragma unroll
      for (int r = 0; r < 4; ++r) {
        const int m = m0 + wm * 32 + i * 16 + quad * 4 + r;
        const int n = wn * 64 + j * 16 + l16;
        out[(size_t)m * XDLD + n] = acc[i][j][r];
      }
}

// ------------- xdbl = sum of KSPLIT partials; also emit dt cols 0..63 as bf16 -------------
__global__ __launch_bounds__(256) void xdbl_reduce(const float* __restrict__ part,
                                                   float* __restrict__ xdbl,
                                                   ushortT* __restrict__ dtb) {
  const int i = blockIdx.x * 256 + threadIdx.x;  // float4 index, [0, 65536)
  float4 a = ((const float4*)part)[i];
#pragma unroll
  for (int s = 1; s < KSPLIT; ++s) {
    const float4 b = ((const float4*)part)[(size_t)s * (B_SZ * L_SZ * XDLD / 4) + i];
    a.x += b.x; a.y += b.y; a.z += b.z; a.w += b.w;
  }
  ((float4*)xdbl)[i] = a;
  // dt = xdbl[:, 0:64] -> compact bf16 [2048][64] for gemm_delta's A operand
  const int row = i >> 5;           // 32 float4 per 128-col row
  const int c4 = (i & 31) * 4;      // column of this float4
  if (c4 < DTR) {
    const unsigned lo = (unsigned)f2bf(a.x) | ((unsigned)f2bf(a.y) << 16);
    const unsigned hi = (unsigned)f2bf(a.z) | ((unsigned)f2bf(a.w) << 16);
    ((uint2*)dtb)[row * (DTR / 4) + (c4 >> 2)] = make_uint2(lo, hi);
  }
}

// ------------- causal depthwise conv (k=4) + silu -> xc bf16 (8-row tiles) -------------
__global__ __launch_bounds__(256) void conv_silu(
    const float* __restrict__ xz, const float* __restrict__ kern,
    const float* __restrict__ bias, ushortT* __restrict__ xcb) {
  const int d = blockIdx.y * 256 + threadIdx.x;
  const int b = blockIdx.x >> 7;           // 128 8-row chunks per batch
  const int l0 = (blockIdx.x & 127) * 8;
  const int row0 = b * L_SZ + l0;
  const float k0v = kern[0 * DI + d], k1v = kern[1 * DI + d];
  const float k2v = kern[2 * DI + d], k3v = kern[3 * DI + d];
  float xv[11];
#pragma unroll
  for (int i = 0; i < 11; ++i) {
    const int l = l0 - 3 + i;
    xv[i] = (l >= 0) ? xz[((size_t)(b * L_SZ + l)) * 4096 + d] : 0.f;
  }
  const float bs = bias[d];
#pragma unroll
  for (int j = 0; j < 8; ++j) {
    float a = bs;
    a = fmaf(xv[j], k0v, a);
    a = fmaf(xv[j + 1], k1v, a);
    a = fmaf(xv[j + 2], k2v, a);
    a = fmaf(xv[j + 3], k3v, a);
    xcb[(size_t)(row0 + j) * DI + d] = f2bf(a / (1.f + __expf(-a)));
  }
}

// ------------- delta = softplus(dt @ Wdt + dt_bias), pure bf16, single K=64 stage -------------
// 64x64 tile, 1024 blocks (4/CU), one barrier pair, fast inline softplus (no log1pf).
__global__ __launch_bounds__(256) void gemm_delta_mfma(
    const ushortT* __restrict__ dtb, const ushortT* __restrict__ WdtT,
    const float* __restrict__ dt_bias, float* __restrict__ delta) {
  __shared__ __align__(16) char smem[64 * 128 + 64 * 128];  // A 8KB | B 8KB
  char* As = smem;
  char* Bs = smem + 64 * 128;
  const int tid = threadIdx.x;
  const int lane = tid & 63;
  const int quad = lane >> 4;
  const int l16 = lane & 15;
  const int wid = tid >> 6;
  const int wm = wid & 1;
  const int wn = wid >> 1;
  const int m0 = blockIdx.x * 64;
  const int n0 = blockIdx.y * 64;

  // Stage A (dt bf16 [64][64]) and B (WdtT [64][64]) — full K=64, one shot.
  for (int i = tid; i < 64 * 8; i += 256) {
    const int r = i >> 3, c = i & 7;
    const int cg = c ^ (r & 7);
    gl2lds16(dtb + (size_t)(m0 + r) * DTR + cg * 8, As + (i - lane) * 16);
  }
  for (int i = tid; i < 64 * 8; i += 256) {
    const int r = i >> 3, c = i & 7;
    const int cg = c ^ (r & 7);
    gl2lds16(WdtT + (size_t)(n0 + r) * DTR + cg * 8, Bs + (i - lane) * 16);
  }
  __syncthreads();

  floatx4 acc[2][2] = {};
  short8 afr[2][2], bfr[2][2];
#pragma unroll
  for (int i = 0; i < 2; ++i) {
    const int m = wm * 32 + i * 16 + l16;
#pragma unroll
    for (int s = 0; s < 2; ++s)
      afr[i][s] = *(const short8*)(As + m * 128 + (((s * 4 + quad) ^ (m & 7)) * 16));
  }
#pragma unroll
  for (int j = 0; j < 2; ++j) {
    const int n = wn * 32 + j * 16 + l16;
#pragma unroll
    for (int s = 0; s < 2; ++s)
      bfr[j][s] = *(const short8*)(Bs + n * 128 + (((s * 4 + quad) ^ (n & 7)) * 16));
  }
#pragma unroll
  for (int s = 0; s < 2; ++s)
#pragma unroll
    for (int i = 0; i < 2; ++i)
#pragma unroll
      for (int j = 0; j < 2; ++j)
        acc[i][j] = __builtin_amdgcn_mfma_f32_16x16x32_bf16(afr[i][s], bfr[j][s],
                                                            acc[i][j], 0, 0, 0);

#pragma unroll
  for (int i = 0; i < 2; ++i)
#pragma unroll
    for (int j = 0; j < 2; ++j) {
      const int n = n0 + wn * 32 + j * 16 + l16;
      const float bias = dt_bias[n];
#pragma unroll
      for (int r = 0; r < 4; ++r) {
        const int m = m0 + wm * 32 + i * 16 + quad * 4 + r;
        const float a = acc[i][j][r] + bias;
        // softplus: a>20 guard covers overflow; expf underflow -> log(1)=0 is exact.
        delta[(size_t)m * DI + n] = (a > 20.f) ? a : __logf(1.f + __expf(a));
      }
    }
}

// ------------- scan phase 1: per-chunk transition -------------
__global__ __launch_bounds__(256) void scan_phase1(
    const float* __restrict__ delta, const ushortT* __restrict__ xcb,
    const float* __restrict__ xdbl, const float* __restrict__ A_log,
    float* __restrict__ xz) {
  const int bx = blockIdx.x;
  const int b = bx >> 9;
  const int c = (bx >> 5) & 15;
  const int dt = bx & 31;
  const int tid = threadIdx.x;
  const int dl = tid >> 2, nq = tid & 3;
  const int d = dt * 64 + dl;
  const int row0 = b * L_SZ + c * CLEN;

  __shared__ float Bsh[CLEN][16];
  for (int i = tid; i < CLEN * 16; i += 256)
    Bsh[i >> 4][i & 15] = xdbl[(size_t)(row0 + (i >> 4)) * XDLD + 64 + (i & 15)];

  float Av[4];
#pragma unroll
  for (int j = 0; j < 4; ++j) Av[j] = -__expf(A_log[d * 16 + nq * 4 + j]);
  float x[4] = {}, P[4] = {1.f, 1.f, 1.f, 1.f};
  __syncthreads();

  const float* dp = delta + (size_t)row0 * DI + d;
  const ushortT* up = xcb + (size_t)row0 * DI + d;
  float dB[4], uB[4];
#pragma unroll
  for (int j = 0; j < 4; ++j) {
    dB[j] = dp[(size_t)j * DI];
    uB[j] = bf2f(up[(size_t)j * DI]);
  }
  for (int l0 = 0; l0 < CLEN; l0 += 4) {
    float dN[4] = {}, uN[4] = {};
    if (l0 + 4 < CLEN) {
#pragma unroll
      for (int j = 0; j < 4; ++j) {
        dN[j] = dp[(size_t)(l0 + 4 + j) * DI];
        uN[j] = bf2f(up[(size_t)(l0 + 4 + j) * DI]);
      }
    }
#pragma unroll
    for (int jj = 0; jj < 4; ++jj) {
      const float dlt = dB[jj];
      const float t = dlt * uB[jj];
      const float* bb = &Bsh[l0 + jj][nq * 4];
#pragma unroll
      for (int n = 0; n < 4; ++n) {
        const float dA = __expf(dlt * Av[n]);
        P[n] *= dA;
        x[n] = fmaf(dA, x[n], t * bb[n]);
      }
    }
#pragma unroll
    for (int j = 0; j < 4; ++j) { dB[j] = dN[j]; uB[j] = uN[j]; }
  }
  const unsigned sb = ((unsigned)((b * NCHUNK + c) * DI + d)) * 16 + nq * 4;
  *(float4*)&xz[stash_addr(sb)] = make_float4(P[0], P[1], P[2], P[3]);
  *(float4*)&xz[stash_addr((1u << 20) + sb)] = make_float4(x[0], x[1], x[2], x[3]);
}

// ------------- scan phase 2: sequential chunk combine -------------
__global__ __launch_bounds__(256) void scan_phase2(float* __restrict__ xz) {
  const int t = blockIdx.x * 256 + threadIdx.x;
  const int b = t >> 15;
  const int rem = t & 32767;
  float x = 0.f;
#pragma unroll
  for (int c = 0; c < NCHUNK; ++c) {
    const unsigned i = ((unsigned)(b * NCHUNK + c) << 15) + rem;
    float* Pr = &xz[stash_addr(i)];
    float* Sr = &xz[stash_addr((1u << 20) + i)];
    const float P = *Pr, S = *Sr;
    *Sr = x;
    x = fmaf(P, x, S);
  }
}

// ------------- scan phase 3: rescan w/ init + y + skip + gate -> bf16 y -------------
__global__ __launch_bounds__(256) void scan_phase3(
    const float* __restrict__ delta, const ushortT* __restrict__ xcb,
    const float* __restrict__ xdbl, const float* __restrict__ A_log,
    const float* __restrict__ Dskip, float* __restrict__ xz) {
  const int bx = blockIdx.x;
  const int b = bx >> 9;
  const int c = (bx >> 5) & 15;
  const int dt = bx & 31;
  const int tid = threadIdx.x;
  const int dl = tid >> 2, nq = tid & 3;
  const int d = dt * 64 + dl;
  const int row0 = b * L_SZ + c * CLEN;

  __shared__ float Bsh[CLEN][16], Csh[CLEN][16];
  for (int i = tid; i < CLEN * 32; i += 256) {
    const int r = i >> 5, q = i & 31;
    const float v = xdbl[(size_t)(row0 + r) * XDLD + 64 + q];
    if (q < 16) Bsh[r][q] = v; else Csh[r][q - 16] = v;
  }

  float Av[4];
#pragma unroll
  for (int j = 0; j < 4; ++j) Av[j] = -__expf(A_log[d * 16 + nq * 4 + j]);
  const float Dsk = Dskip[d];
  const unsigned sb = ((unsigned)((b * NCHUNK + c) * DI + d)) * 16 + nq * 4;
  const float4 xi = *(const float4*)&xz[stash_addr((1u << 20) + sb)];
  float x[4] = {xi.x, xi.y, xi.z, xi.w};
  __syncthreads();

  const float* dp = delta + (size_t)row0 * DI + d;
  const ushortT* up = xcb + (size_t)row0 * DI + d;
  const float* zp = xz + (size_t)row0 * 4096 + DI + d;
  ushortT* yb = (ushortT*)xz;

  float dB[4], uB[4], zB[4];
#pragma unroll
  for (int j = 0; j < 4; ++j) {
    dB[j] = dp[(size_t)j * DI];
    uB[j] = bf2f(up[(size_t)j * DI]);
    zB[j] = zp[(size_t)j * 4096];
  }
  for (int l0 = 0; l0 < CLEN; l0 += 4) {
    float dN[4] = {}, uN[4] = {}, zN[4] = {};
    if (l0 + 4 < CLEN) {
#pragma unroll
      for (int j = 0; j < 4; ++j) {
        dN[j] = dp[(size_t)(l0 + 4 + j) * DI];
        uN[j] = bf2f(up[(size_t)(l0 + 4 + j) * DI]);
        zN[j] = zp[(size_t)(l0 + 4 + j) * 4096];
      }
    }
#pragma unroll
    for (int jj = 0; jj < 4; ++jj) {
      const float dlt = dB[jj];
      const float u = uB[jj];
      const float t = dlt * u;
      const float* bb = &Bsh[l0 + jj][nq * 4];
      const float* cc = &Csh[l0 + jj][nq * 4];
      float y = 0.f;
#pragma unroll
      for (int n = 0; n < 4; ++n) {
        const float dA = __expf(dlt * Av[n]);
        x[n] = fmaf(dA, x[n], t * bb[n]);
        y = fmaf(x[n], cc[n], y);
      }
      y += __shfl_xor(y, 1);
      y += __shfl_xor(y, 2);
      if (nq == 0) {
        const float z = zB[jj];
        const float g = (y + u * Dsk) * (z / (1.f + __expf(-z)));
        yb[(size_t)(row0 + l0 + jj) * 8192 + d] = f2bf(g);
      }
    }
#pragma unroll
    for (int j = 0; j < 4; ++j) { dB[j] = dN[j]; uB[j] = uN[j]; zB[j] = zN[j]; }
  }
}

extern "C" void kernel_launch(void* const* d_in, const int* in_sizes, int n_in,
                              void* d_out, int out_size, void* d_ws, size_t ws_size,
                              hipStream_t stream) {
  const float* hidden  = (const float*)d_in[0];
  const float* Win     = (const float*)d_in[1];
  const float* Wx      = (const float*)d_in[2];
  const float* Wdt     = (const float*)d_in[3];
  const float* dt_bias = (const float*)d_in[4];
  const float* Wout    = (const float*)d_in[5];
  const float* dwk     = (const float*)d_in[6];
  const float* dwb     = (const float*)d_in[7];
  const float* A_log   = (const float*)d_in[8];
  const float* Dskip   = (const float*)d_in[9];

  // ws (64 MB): xz 32MB | shared16 (WinT -> xdbl partials -> delta -> WoutT) 16MB
  //             | xc region 16MB: bf16 xc [0,8M); GEMM4 split-K partials reuse all 16MB
  // xz per-row float layout: [0,1024) y-bf16 | [1024,2048) scan stash | [2048,4096) z
  char* ws = (char*)d_ws;
  float* xz       = (float*)ws;
  float* shared16 = (float*)(ws + (32u << 20));
  float* xcreg    = (float*)(ws + (48u << 20));
  ushortT* xcb    = (ushortT*)xcreg;
  // d_out (8 MB) scratch: hidb [0,4M) (dead after GEMM1); xdbl128 [4M,5M);
  //                       WxT [5M,5.5M); WdtT [5.5M,5.75M); dtb [5.75M,6M)
  char* dob = (char*)d_out;
  ushortT* hidb = (ushortT*)dob;
  float* xdbl   = (float*)(dob + (4u << 20));
  ushortT* WxT  = (ushortT*)(dob + (5u << 20));
  ushortT* WdtT = (ushortT*)(dob + (5u << 20) + (512u << 10));
  ushortT* dtb  = (ushortT*)(dob + (5u << 20) + (768u << 10));

  // 1. hidden -> bf16
  cvt_bf16<<<dim3(B_SZ * L_SZ * DM / 1024), 256, 0, stream>>>(hidden, hidb);
  // 2. Win (1024x4096) -> WinT bf16 (4096x1024) in shared16
  transpose_bf16<<<dim3(4096 / 32, 1024 / 32), dim3(32, 8), 0, stream>>>(
      Win, (ushortT*)shared16, DM, 2 * DI);
  // 3. Wx -> WxT bf16 padded (128 x 2048); Wdt (64x2048) -> WdtT bf16 (2048x64)
  wx_pad_t<<<dim3(DI / 256, 128), 256, 0, stream>>>(Wx, WxT);
  transpose_bf16<<<dim3(DI / 32, DTR / 32), dim3(32, 8), 0, stream>>>(
      Wdt, WdtT, DTR, DI);
  // 4. GEMM1: xz = hidden @ Win  (M=2048, N=4096, K=1024); 128x128, 8 waves, 512 blocks
  gemm1_big<<<dim3(4096 / 128, 2048 / 128), 512, 0, stream>>>(
      hidb, DM, (ushortT*)shared16, DM, xz, 2 * DI, DM);
  // 5. depthwise conv + silu -> xc bf16 (8-row tiles)
  conv_silu<<<dim3(B_SZ * L_SZ / 8, DI / 256), 256, 0, stream>>>(xz, dwk, dwb, xcb);
  // 6. x_dbl partials (K-split 16) -> shared16 [0,16M) (WinT dead), then reduce (+dt bf16)
  gemm_xdbl_mfma<<<dim3(B_SZ * L_SZ / 64, KSPLIT), 256, 0, stream>>>(
      xcb, WxT, shared16);
  xdbl_reduce<<<dim3(B_SZ * L_SZ * XDLD / 1024), 256, 0, stream>>>(shared16, xdbl, dtb);
  // 7. delta = softplus(dt @ Wdt + bias): pure-bf16 MFMA, single K=64 stage, 1024 blocks
  gemm_delta_mfma<<<dim3(B_SZ * L_SZ / 64, DI / 64), 256, 0, stream>>>(
      dtb, WdtT, dt_bias, shared16);
  // 8-10. chunked selective scan (states in xz stash); y (gated, bf16) -> xz
  scan_phase1<<<dim3(B_SZ * NCHUNK * (DI / 64)), 256, 0, stream>>>(
      shared16, xcb, xdbl, A_log, xz);
  scan_phase2<<<dim3(B_SZ * DI * NS / 256), 256, 0, stream>>>(xz);
  scan_phase3<<<dim3(B_SZ * NCHUNK * (DI / 64)), 256, 0, stream>>>(
      shared16, xcb, xdbl, A_log, Dskip, xz);
  // 11. Wout (2048x1024) -> WoutT bf16 (1024x2048) in shared16 (delta dead)
  transpose_bf16<<<dim3(1024 / 32, 2048 / 32), dim3(32, 8), 0, stream>>>(
      Wout, (ushortT*)shared16, DI, DM);
  // 12. GEMM4 split-K=2: partials -> xc region (dead after scan), then reduce -> d_out
  gemm_out_split<<<dim3(1024 / 64, 2048 / 64, 2), 256, 0, stream>>>(
      (ushortT*)xz, 4 * DI, (ushortT*)shared16, DI, xcreg);
  reduce_out<<<dim3(B_SZ * L_SZ * DM / 1024), 256, 0, stream>>>(xcreg, (float*)d_out);
}

// Round 3
// 231.722 us; speedup vs baseline: 1.1099x; 1.0330x over previous
//
#include <hip/hip_runtime.h>
#include <hip/hip_bf16.h>
#include <math.h>

#define B_SZ 2
#define L_SZ 1024
#define DM 1024
#define DI 2048
#define NS 16
#define DTR 64
#define NCHUNK 16
#define CLEN 64
#define XDLD 128  // padded x_dbl leading dim
#define KSPLIT 8

typedef unsigned short ushortT;
typedef __attribute__((ext_vector_type(8))) short short8;
typedef __attribute__((ext_vector_type(4))) float floatx4;

__device__ __forceinline__ ushortT f2bf(float f) {
  unsigned u = __float_as_uint(f);
  unsigned r = (u + 0x7fff + ((u >> 16) & 1)) >> 16;
  return (ushortT)r;
}

__device__ __forceinline__ float bf2f(ushortT v) {
  return __uint_as_float((unsigned)v << 16);
}

__device__ __forceinline__ void gl2lds16(const void* g, void* l) {
  __builtin_amdgcn_global_load_lds(
      (const __attribute__((address_space(1))) unsigned int*)g,
      (__attribute__((address_space(3))) unsigned int*)l, 16, 0, 0);
}

// Scan-state stash lives in the dead strided region of xz: floats [1024,2048)
// of each 4096-float row. i in [0, 2M): aprod at i, sfin at i + 1M.
__device__ __forceinline__ unsigned stash_addr(unsigned i) {
  return (i >> 10) * 4096 + 1024 + (i & 1023);
}

// ---------------- fused prep: cvt + 3 transposes + wx_pad ----------------
__device__ __forceinline__ void tr_body(const float* __restrict__ src,
                                        ushortT* __restrict__ dst, int R, int C,
                                        int bx, int by, int tx, int ty,
                                        float (*t)[33]) {
#pragma unroll
  for (int j = 0; j < 4; ++j)
    t[ty + j * 8][tx] = src[(size_t)(by + ty + j * 8) * C + bx + tx];
  __syncthreads();
#pragma unroll
  for (int j = 0; j < 4; ++j)
    dst[(size_t)(bx + ty + j * 8) * R + by + tx] = f2bf(t[tx][ty + j * 8]);
}

// grid ranges: [0,2048) cvt hidden | [2048,6144) Win-T | [6144,7168) Wx pad-T
//              [7168,7296) Wdt-T | [7296,9344) Wout-T
__global__ __launch_bounds__(256) void prep_all(
    const float* __restrict__ hidden, ushortT* __restrict__ hidb,
    const float* __restrict__ Win, ushortT* __restrict__ WinT,
    const float* __restrict__ Wx, ushortT* __restrict__ WxT,
    const float* __restrict__ Wdt, ushortT* __restrict__ WdtT,
    const float* __restrict__ Wout, ushortT* __restrict__ WoutT) {
  __shared__ float t[32][33];
  const int blk = blockIdx.x;
  const int tid = threadIdx.x;
  const int tx = tid & 31, ty = tid >> 5;
  if (blk < 2048) {
    const int i = blk * 256 + tid;
    float4 v = ((const float4*)hidden)[i];
    unsigned lo = (unsigned)f2bf(v.x) | ((unsigned)f2bf(v.y) << 16);
    unsigned hi = (unsigned)f2bf(v.z) | ((unsigned)f2bf(v.w) << 16);
    ((uint2*)hidb)[i] = make_uint2(lo, hi);
  } else if (blk < 6144) {
    const int rel = blk - 2048;  // (128, 32): C=4096, R=1024
    tr_body(Win, WinT, DM, 2 * DI, (rel & 127) * 32, (rel >> 7) * 32, tx, ty, t);
  } else if (blk < 7168) {
    const int rel = blk - 6144;  // (8, 128)
    const int k = (rel & 7) * 256 + tid;
    const int n = rel >> 3;
    WxT[(size_t)n * DI + k] = (n < 96) ? f2bf(Wx[(size_t)k * 96 + n]) : (ushortT)0;
  } else if (blk < 7296) {
    const int rel = blk - 7168;  // (64, 2): C=2048, R=64
    tr_body(Wdt, WdtT, DTR, DI, (rel & 63) * 32, (rel >> 6) * 32, tx, ty, t);
  } else {
    const int rel = blk - 7296;  // (32, 64): C=1024, R=2048
    tr_body(Wout, WoutT, DI, DM, (rel & 31) * 32, (rel >> 5) * 32, tx, ty, t);
  }
}

// ---------------- GEMM1: 128x128 tile, BK=64, 8 waves (512 thr), 512 blocks ----------------
__global__ __launch_bounds__(512) void gemm1_big(
    const ushortT* __restrict__ A, int lda,
    const ushortT* __restrict__ BT, int ldb,
    float* __restrict__ C, int ldc, int K) {
  __shared__ __align__(16) char smem[128 * 128 + 128 * 128];  // A 16KB | B 16KB
  char* As = smem;
  char* Bs = smem + 128 * 128;
  const int tid = threadIdx.x;
  const int lane = tid & 63;
  const int quad = lane >> 4;
  const int l16 = lane & 15;
  const int wid = tid >> 6;
  const int wm = wid & 1;   // 2 m-halves of 64
  const int wn = wid >> 1;  // 4 n-quarters of 32
  const int m0 = blockIdx.y * 128;
  const int n0 = blockIdx.x * 128;

  floatx4 acc[4][2] = {};

  for (int k0 = 0; k0 < K; k0 += 64) {
    for (int i = tid; i < 128 * 8; i += 512) {
      const int r = i >> 3, c = i & 7;
      const int cg = c ^ (r & 7);
      gl2lds16(A + (size_t)(m0 + r) * lda + k0 + cg * 8, As + (i - lane) * 16);
    }
    for (int i = tid; i < 128 * 8; i += 512) {
      const int r = i >> 3, c = i & 7;
      const int cg = c ^ (r & 7);
      gl2lds16(BT + (size_t)(n0 + r) * ldb + k0 + cg * 8, Bs + (i - lane) * 16);
    }
    __syncthreads();

    short8 afr[4][2], bfr[2][2];
#pragma unroll
    for (int i = 0; i < 4; ++i) {
      const int r = wm * 64 + i * 16 + l16;
#pragma unroll
      for (int s = 0; s < 2; ++s)
        afr[i][s] = *(const short8*)(As + r * 128 + (((s * 4 + quad) ^ (r & 7)) * 16));
    }
#pragma unroll
    for (int j = 0; j < 2; ++j) {
      const int r = wn * 32 + j * 16 + l16;
#pragma unroll
      for (int s = 0; s < 2; ++s)
        bfr[j][s] = *(const short8*)(Bs + r * 128 + (((s * 4 + quad) ^ (r & 7)) * 16));
    }
#pragma unroll
    for (int s = 0; s < 2; ++s)
#pragma unroll
      for (int i = 0; i < 4; ++i)
#pragma unroll
        for (int j = 0; j < 2; ++j)
          acc[i][j] = __builtin_amdgcn_mfma_f32_16x16x32_bf16(afr[i][s], bfr[j][s],
                                                              acc[i][j], 0, 0, 0);
    __syncthreads();
  }
#pragma unroll
  for (int i = 0; i < 4; ++i)
#pragma unroll
    for (int j = 0; j < 2; ++j)
#pragma unroll
      for (int r = 0; r < 4; ++r) {
        const int m = m0 + wm * 64 + i * 16 + quad * 4 + r;
        const int n = n0 + wn * 32 + j * 16 + l16;
        C[(size_t)m * ldc + n] = acc[i][j][r];
      }
}

// ---------------- GEMM4: 64x64 tile, BK=64, K=2048, 4 waves, 512 blocks, direct out --------
__global__ __launch_bounds__(256) void gemm_out(
    const ushortT* __restrict__ A, int lda,
    const ushortT* __restrict__ BT, int ldb,
    float* __restrict__ C) {
  __shared__ __align__(16) char smem[64 * 128 + 64 * 128];  // 8KB + 8KB
  char* As = smem;
  char* Bs = smem + 64 * 128;
  const int tid = threadIdx.x;
  const int lane = tid & 63;
  const int quad = lane >> 4;
  const int l16 = lane & 15;
  const int wid = tid >> 6;
  const int wm = wid & 1;   // 2 m-halves of 32
  const int wn = wid >> 1;  // 2 n-halves of 32
  const int m0 = blockIdx.y * 64;
  const int n0 = blockIdx.x * 64;

  floatx4 acc[2][2] = {};

  for (int k0 = 0; k0 < DI; k0 += 64) {
    for (int i = tid; i < 64 * 8; i += 256) {
      const int r = i >> 3, c = i & 7;
      const int cg = c ^ (r & 7);
      gl2lds16(A + (size_t)(m0 + r) * lda + k0 + cg * 8, As + (i - lane) * 16);
    }
    for (int i = tid; i < 64 * 8; i += 256) {
      const int r = i >> 3, c = i & 7;
      const int cg = c ^ (r & 7);
      gl2lds16(BT + (size_t)(n0 + r) * ldb + k0 + cg * 8, Bs + (i - lane) * 16);
    }
    __syncthreads();

    short8 afr[2][2], bfr[2][2];
#pragma unroll
    for (int i = 0; i < 2; ++i) {
      const int m = wm * 32 + i * 16 + l16;
#pragma unroll
      for (int s = 0; s < 2; ++s)
        afr[i][s] = *(const short8*)(As + m * 128 + (((s * 4 + quad) ^ (m & 7)) * 16));
    }
#pragma unroll
    for (int j = 0; j < 2; ++j) {
      const int n = wn * 32 + j * 16 + l16;
#pragma unroll
      for (int s = 0; s < 2; ++s)
        bfr[j][s] = *(const short8*)(Bs + n * 128 + (((s * 4 + quad) ^ (n & 7)) * 16));
    }
#pragma unroll
    for (int s = 0; s < 2; ++s)
#pragma unroll
      for (int i = 0; i < 2; ++i)
#pragma unroll
        for (int j = 0; j < 2; ++j)
          acc[i][j] = __builtin_amdgcn_mfma_f32_16x16x32_bf16(afr[i][s], bfr[j][s],
                                                              acc[i][j], 0, 0, 0);
    __syncthreads();
  }
#pragma unroll
  for (int i = 0; i < 2; ++i)
#pragma unroll
    for (int j = 0; j < 2; ++j)
#pragma unroll
      for (int r = 0; r < 4; ++r) {
        const int m = m0 + wm * 32 + i * 16 + quad * 4 + r;
        const int n = n0 + wn * 32 + j * 16 + l16;
        C[(size_t)m * DM + n] = acc[i][j][r];
      }
}

// ------------- x_dbl partials: xc(bf16) @ Wx (padded N=128), K-split via MFMA -------------
__global__ __launch_bounds__(256) void gemm_xdbl_mfma(
    const ushortT* __restrict__ xcb, const ushortT* __restrict__ WxT,
    float* __restrict__ part) {
  __shared__ __align__(16) char smem[64 * 64 + 128 * 64];
  char* As = smem;             // [64 r][64 B bf16]
  char* Bs = smem + 64 * 64;   // [128 r][64 B bf16]
  const int tid = threadIdx.x;
  const int lane = tid & 63;
  const int quad = lane >> 4;
  const int l16 = lane & 15;
  const int wid = tid >> 6;
  const int wm = wid & 1;
  const int wn = wid >> 1;
  const int m0 = blockIdx.x * 64;
  const int kbase = blockIdx.y * (DI / KSPLIT);

  floatx4 acc[2][4] = {};

  for (int kk = 0; kk < DI / KSPLIT; kk += 32) {
    const int k0 = kbase + kk;
    for (int i = tid; i < 64 * 4; i += 256) {
      const int r = i >> 2, c = i & 3;
      const int cg = c ^ (r & 3);
      gl2lds16(xcb + (size_t)(m0 + r) * DI + k0 + cg * 8, As + (i - lane) * 16);
    }
    for (int i = tid; i < 128 * 4; i += 256) {
      const int r = i >> 2, c = i & 3;
      const int cg = c ^ (r & 3);
      gl2lds16(WxT + (size_t)r * DI + k0 + cg * 8, Bs + (i - lane) * 16);
    }
    __syncthreads();

    short8 afr[2], bfr[4];
#pragma unroll
    for (int i = 0; i < 2; ++i) {
      const int m = wm * 32 + i * 16 + l16;
      afr[i] = *(const short8*)(As + m * 64 + ((quad ^ (m & 3)) * 16));
    }
#pragma unroll
    for (int j = 0; j < 4; ++j) {
      const int n = wn * 64 + j * 16 + l16;
      bfr[j] = *(const short8*)(Bs + n * 64 + ((quad ^ (n & 3)) * 16));
    }
#pragma unroll
    for (int i = 0; i < 2; ++i)
#pragma unroll
      for (int j = 0; j < 4; ++j)
        acc[i][j] = __builtin_amdgcn_mfma_f32_16x16x32_bf16(afr[i], bfr[j],
                                                            acc[i][j], 0, 0, 0);
    __syncthreads();
  }
  float* out = part + (size_t)blockIdx.y * (B_SZ * L_SZ * XDLD);
#pragma unroll
  for (int i = 0; i < 2; ++i)
#pragma unroll
    for (int j = 0; j < 4; ++j)
#pragma unroll
      for (int r = 0; r < 4; ++r) {
        const int m = m0 + wm * 32 + i * 16 + quad * 4 + r;
        const int n = wn * 64 + j * 16 + l16;
        out[(size_t)m * XDLD + n] = acc[i][j][r];
      }
}

// ------------- xdbl = sum of KSPLIT partials; also emit dt cols 0..63 as bf16 -------------
__global__ __launch_bounds__(256) void xdbl_reduce(const float* __restrict__ part,
                                                   float* __restrict__ xdbl,
                                                   ushortT* __restrict__ dtb) {
  const int i = blockIdx.x * 256 + threadIdx.x;  // float4 index, [0, 65536)
  float4 a = ((const float4*)part)[i];
#pragma unroll
  for (int s = 1; s < KSPLIT; ++s) {
    const float4 b = ((const float4*)part)[(size_t)s * (B_SZ * L_SZ * XDLD / 4) + i];
    a.x += b.x; a.y += b.y; a.z += b.z; a.w += b.w;
  }
  ((float4*)xdbl)[i] = a;
  // dt = xdbl[:, 0:64] -> compact bf16 [2048][64] for gemm_delta's A operand
  const int row = i >> 5;           // 32 float4 per 128-col row
  const int c4 = (i & 31) * 4;      // column of this float4
  if (c4 < DTR) {
    const unsigned lo = (unsigned)f2bf(a.x) | ((unsigned)f2bf(a.y) << 16);
    const unsigned hi = (unsigned)f2bf(a.z) | ((unsigned)f2bf(a.w) << 16);
    ((uint2*)dtb)[row * (DTR / 4) + (c4 >> 2)] = make_uint2(lo, hi);
  }
}

// ------------- causal depthwise conv (k=4) + silu -> xc bf16 (8-row tiles) -------------
__global__ __launch_bounds__(256) void conv_silu(
    const float* __restrict__ xz, const float* __restrict__ kern,
    const float* __restrict__ bias, ushortT* __restrict__ xcb) {
  const int d = blockIdx.y * 256 + threadIdx.x;
  const int b = blockIdx.x >> 7;           // 128 8-row chunks per batch
  const int l0 = (blockIdx.x & 127) * 8;
  const int row0 = b * L_SZ + l0;
  const float k0v = kern[0 * DI + d], k1v = kern[1 * DI + d];
  const float k2v = kern[2 * DI + d], k3v = kern[3 * DI + d];
  float xv[11];
#pragma unroll
  for (int i = 0; i < 11; ++i) {
    const int l = l0 - 3 + i;
    xv[i] = (l >= 0) ? xz[((size_t)(b * L_SZ + l)) * 4096 + d] : 0.f;
  }
  const float bs = bias[d];
#pragma unroll
  for (int j = 0; j < 8; ++j) {
    float a = bs;
    a = fmaf(xv[j], k0v, a);
    a = fmaf(xv[j + 1], k1v, a);
    a = fmaf(xv[j + 2], k2v, a);
    a = fmaf(xv[j + 3], k3v, a);
    xcb[(size_t)(row0 + j) * DI + d] = f2bf(a / (1.f + __expf(-a)));
  }
}

// ------------- delta = softplus(dt @ Wdt + dt_bias), pure bf16, single K=64 stage -------------
__global__ __launch_bounds__(256) void gemm_delta_mfma(
    const ushortT* __restrict__ dtb, const ushortT* __restrict__ WdtT,
    const float* __restrict__ dt_bias, float* __restrict__ delta) {
  __shared__ __align__(16) char smem[64 * 128 + 64 * 128];  // A 8KB | B 8KB
  char* As = smem;
  char* Bs = smem + 64 * 128;
  const int tid = threadIdx.x;
  const int lane = tid & 63;
  const int quad = lane >> 4;
  const int l16 = lane & 15;
  const int wid = tid >> 6;
  const int wm = wid & 1;
  const int wn = wid >> 1;
  const int m0 = blockIdx.x * 64;
  const int n0 = blockIdx.y * 64;

  // Stage A (dt bf16 [64][64]) and B (WdtT [64][64]) — full K=64, one shot.
  for (int i = tid; i < 64 * 8; i += 256) {
    const int r = i >> 3, c = i & 7;
    const int cg = c ^ (r & 7);
    gl2lds16(dtb + (size_t)(m0 + r) * DTR + cg * 8, As + (i - lane) * 16);
  }
  for (int i = tid; i < 64 * 8; i += 256) {
    const int r = i >> 3, c = i & 7;
    const int cg = c ^ (r & 7);
    gl2lds16(WdtT + (size_t)(n0 + r) * DTR + cg * 8, Bs + (i - lane) * 16);
  }
  __syncthreads();

  floatx4 acc[2][2] = {};
  short8 afr[2][2], bfr[2][2];
#pragma unroll
  for (int i = 0; i < 2; ++i) {
    const int m = wm * 32 + i * 16 + l16;
#pragma unroll
    for (int s = 0; s < 2; ++s)
      afr[i][s] = *(const short8*)(As + m * 128 + (((s * 4 + quad) ^ (m & 7)) * 16));
  }
#pragma unroll
  for (int j = 0; j < 2; ++j) {
    const int n = wn * 32 + j * 16 + l16;
#pragma unroll
    for (int s = 0; s < 2; ++s)
      bfr[j][s] = *(const short8*)(Bs + n * 128 + (((s * 4 + quad) ^ (n & 7)) * 16));
  }
#pragma unroll
  for (int s = 0; s < 2; ++s)
#pragma unroll
    for (int i = 0; i < 2; ++i)
#pragma unroll
      for (int j = 0; j < 2; ++j)
        acc[i][j] = __builtin_amdgcn_mfma_f32_16x16x32_bf16(afr[i][s], bfr[j][s],
                                                            acc[i][j], 0, 0, 0);

#pragma unroll
  for (int i = 0; i < 2; ++i)
#pragma unroll
    for (int j = 0; j < 2; ++j) {
      const int n = n0 + wn * 32 + j * 16 + l16;
      const float bias = dt_bias[n];
#pragma unroll
      for (int r = 0; r < 4; ++r) {
        const int m = m0 + wm * 32 + i * 16 + quad * 4 + r;
        const float a = acc[i][j][r] + bias;
        // softplus: a>20 guard covers overflow; expf underflow -> log(1)=0 is exact.
        delta[(size_t)m * DI + n] = (a > 20.f) ? a : __logf(1.f + __expf(a));
      }
    }
}

// ------------- scan phase 1: per-chunk transition -------------
__global__ __launch_bounds__(256) void scan_phase1(
    const float* __restrict__ delta, const ushortT* __restrict__ xcb,
    const float* __restrict__ xdbl, const float* __restrict__ A_log,
    float* __restrict__ xz) {
  const int bx = blockIdx.x;
  const int b = bx >> 9;
  const int c = (bx >> 5) & 15;
  const int dt = bx & 31;
  const int tid = threadIdx.x;
  const int dl = tid >> 2, nq = tid & 3;
  const int d = dt * 64 + dl;
  const int row0 = b * L_SZ + c * CLEN;

  __shared__ float Bsh[CLEN][16];
  for (int i = tid; i < CLEN * 16; i += 256)
    Bsh[i >> 4][i & 15] = xdbl[(size_t)(row0 + (i >> 4)) * XDLD + 64 + (i & 15)];

  float Av[4];
#pragma unroll
  for (int j = 0; j < 4; ++j) Av[j] = -__expf(A_log[d * 16 + nq * 4 + j]);
  float x[4] = {}, P[4] = {1.f, 1.f, 1.f, 1.f};
  __syncthreads();

  const float* dp = delta + (size_t)row0 * DI + d;
  const ushortT* up = xcb + (size_t)row0 * DI + d;
  float dB[4], uB[4];
#pragma unroll
  for (int j = 0; j < 4; ++j) {
    dB[j] = dp[(size_t)j * DI];
    uB[j] = bf2f(up[(size_t)j * DI]);
  }
  for (int l0 = 0; l0 < CLEN; l0 += 4) {
    float dN[4] = {}, uN[4] = {};
    if (l0 + 4 < CLEN) {
#pragma unroll
      for (int j = 0; j < 4; ++j) {
        dN[j] = dp[(size_t)(l0 + 4 + j) * DI];
        uN[j] = bf2f(up[(size_t)(l0 + 4 + j) * DI]);
      }
    }
#pragma unroll
    for (int jj = 0; jj < 4; ++jj) {
      const float dlt = dB[jj];
      const float t = dlt * uB[jj];
      const float* bb = &Bsh[l0 + jj][nq * 4];
#pragma unroll
      for (int n = 0; n < 4; ++n) {
        const float dA = __expf(dlt * Av[n]);
        P[n] *= dA;
        x[n] = fmaf(dA, x[n], t * bb[n]);
      }
    }
#pragma unroll
    for (int j = 0; j < 4; ++j) { dB[j] = dN[j]; uB[j] = uN[j]; }
  }
  const unsigned sb = ((unsigned)((b * NCHUNK + c) * DI + d)) * 16 + nq * 4;
  *(float4*)&xz[stash_addr(sb)] = make_float4(P[0], P[1], P[2], P[3]);
  *(float4*)&xz[stash_addr((1u << 20) + sb)] = make_float4(x[0], x[1], x[2], x[3]);
}

// ------------- scan phase 3: chunk-init combine + rescan + y + skip + gate -> bf16 y -------
__global__ __launch_bounds__(256) void scan_phase3(
    const float* __restrict__ delta, const ushortT* __restrict__ xcb,
    const float* __restrict__ xdbl, const float* __restrict__ A_log,
    const float* __restrict__ Dskip, float* __restrict__ xz) {
  const int bx = blockIdx.x;
  const int b = bx >> 9;
  const int c = (bx >> 5) & 15;
  const int dt = bx & 31;
  const int tid = threadIdx.x;
  const int dl = tid >> 2, nq = tid & 3;
  const int d = dt * 64 + dl;
  const int row0 = b * L_SZ + c * CLEN;

  __shared__ float Bsh[CLEN][16], Csh[CLEN][16];
  for (int i = tid; i < CLEN * 32; i += 256) {
    const int r = i >> 5, q = i & 31;
    const float v = xdbl[(size_t)(row0 + r) * XDLD + 64 + q];
    if (q < 16) Bsh[r][q] = v; else Csh[r][q - 16] = v;
  }

  float Av[4];
#pragma unroll
  for (int j = 0; j < 4; ++j) Av[j] = -__expf(A_log[d * 16 + nq * 4 + j]);
  const float Dsk = Dskip[d];

  // chunk-init: combine P/S of chunks < c (was scan_phase2) — identical fma order.
  float x[4] = {0.f, 0.f, 0.f, 0.f};
  for (int cc = 0; cc < c; ++cc) {
    const unsigned ib = ((unsigned)((b * NCHUNK + cc) * DI + d)) * 16 + nq * 4;
    const float4 P = *(const float4*)&xz[stash_addr(ib)];
    const float4 S = *(const float4*)&xz[stash_addr((1u << 20) + ib)];
    x[0] = fmaf(P.x, x[0], S.x);
    x[1] = fmaf(P.y, x[1], S.y);
    x[2] = fmaf(P.z, x[2], S.z);
    x[3] = fmaf(P.w, x[3], S.w);
  }
  __syncthreads();

  const float* dp = delta + (size_t)row0 * DI + d;
  const ushortT* up = xcb + (size_t)row0 * DI + d;
  const float* zp = xz + (size_t)row0 * 4096 + DI + d;
  ushortT* yb = (ushortT*)xz;

  float dB[4], uB[4], zB[4];
#pragma unroll
  for (int j = 0; j < 4; ++j) {
    dB[j] = dp[(size_t)j * DI];
    uB[j] = bf2f(up[(size_t)j * DI]);
    zB[j] = zp[(size_t)j * 4096];
  }
  for (int l0 = 0; l0 < CLEN; l0 += 4) {
    float dN[4] = {}, uN[4] = {}, zN[4] = {};
    if (l0 + 4 < CLEN) {
#pragma unroll
      for (int j = 0; j < 4; ++j) {
        dN[j] = dp[(size_t)(l0 + 4 + j) * DI];
        uN[j] = bf2f(up[(size_t)(l0 + 4 + j) * DI]);
        zN[j] = zp[(size_t)(l0 + 4 + j) * 4096];
      }
    }
#pragma unroll
    for (int jj = 0; jj < 4; ++jj) {
      const float dlt = dB[jj];
      const float u = uB[jj];
      const float t = dlt * u;
      const float* bb = &Bsh[l0 + jj][nq * 4];
      const float* cc = &Csh[l0 + jj][nq * 4];
      float y = 0.f;
#pragma unroll
      for (int n = 0; n < 4; ++n) {
        const float dA = __expf(dlt * Av[n]);
        x[n] = fmaf(dA, x[n], t * bb[n]);
        y = fmaf(x[n], cc[n], y);
      }
      y += __shfl_xor(y, 1);
      y += __shfl_xor(y, 2);
      if (nq == 0) {
        const float z = zB[jj];
        const float g = (y + u * Dsk) * (z / (1.f + __expf(-z)));
        yb[(size_t)(row0 + l0 + jj) * 8192 + d] = f2bf(g);
      }
    }
#pragma unroll
    for (int j = 0; j < 4; ++j) { dB[j] = dN[j]; uB[j] = uN[j]; zB[j] = zN[j]; }
  }
}

extern "C" void kernel_launch(void* const* d_in, const int* in_sizes, int n_in,
                              void* d_out, int out_size, void* d_ws, size_t ws_size,
                              hipStream_t stream) {
  const float* hidden  = (const float*)d_in[0];
  const float* Win     = (const float*)d_in[1];
  const float* Wx      = (const float*)d_in[2];
  const float* Wdt     = (const float*)d_in[3];
  const float* dt_bias = (const float*)d_in[4];
  const float* Wout    = (const float*)d_in[5];
  const float* dwk     = (const float*)d_in[6];
  const float* dwb     = (const float*)d_in[7];
  const float* A_log   = (const float*)d_in[8];
  const float* Dskip   = (const float*)d_in[9];

  // ws (64 MB): xz 32MB | shared16 (WinT -> xdbl partials -> delta) 16MB
  //             | [48,56M) xcb bf16 | [56,60M) WoutT bf16 | [60,64M) free
  // xz per-row float layout: [0,1024) y-bf16 | [1024,2048) scan stash | [2048,4096) z
  char* ws = (char*)d_ws;
  float* xz       = (float*)ws;
  float* shared16 = (float*)(ws + (32u << 20));
  ushortT* xcb    = (ushortT*)(ws + (48u << 20));
  ushortT* WoutT  = (ushortT*)(ws + (56u << 20));
  // d_out (8 MB) scratch: hidb [0,4M) (dead after GEMM1); xdbl128 [4M,5M);
  //                       WxT [5M,5.5M); WdtT [5.5M,5.75M); dtb [5.75M,6M)
  // all dead before gemm_out overwrites d_out with the final result.
  char* dob = (char*)d_out;
  ushortT* hidb = (ushortT*)dob;
  float* xdbl   = (float*)(dob + (4u << 20));
  ushortT* WxT  = (ushortT*)(dob + (5u << 20));
  ushortT* WdtT = (ushortT*)(dob + (5u << 20) + (512u << 10));
  ushortT* dtb  = (ushortT*)(dob + (5u << 20) + (768u << 10));

  // 1. fused prep: hidden->bf16, Win^T, Wx pad^T, Wdt^T, Wout^T
  prep_all<<<dim3(9344), 256, 0, stream>>>(hidden, hidb, Win, (ushortT*)shared16,
                                           Wx, WxT, Wdt, WdtT, Wout, WoutT);
  // 2. GEMM1: xz = hidden @ Win  (M=2048, N=4096, K=1024); 128x128, 8 waves, 512 blocks
  gemm1_big<<<dim3(4096 / 128, 2048 / 128), 512, 0, stream>>>(
      hidb, DM, (ushortT*)shared16, DM, xz, 2 * DI, DM);
  // 3. depthwise conv + silu -> xc bf16 (8-row tiles)
  conv_silu<<<dim3(B_SZ * L_SZ / 8, DI / 256), 256, 0, stream>>>(xz, dwk, dwb, xcb);
  // 4. x_dbl partials (K-split 8) -> shared16 [0,8M) (WinT dead), then reduce (+dt bf16)
  gemm_xdbl_mfma<<<dim3(B_SZ * L_SZ / 64, KSPLIT), 256, 0, stream>>>(
      xcb, WxT, shared16);
  xdbl_reduce<<<dim3(B_SZ * L_SZ * XDLD / 1024), 256, 0, stream>>>(shared16, xdbl, dtb);
  // 5. delta = softplus(dt @ Wdt + bias): pure-bf16 MFMA, single K=64 stage, 1024 blocks
  gemm_delta_mfma<<<dim3(B_SZ * L_SZ / 64, DI / 64), 256, 0, stream>>>(
      dtb, WdtT, dt_bias, shared16);
  // 6-7. chunked selective scan (states in xz stash); phase3 folds the chunk combine
  scan_phase1<<<dim3(B_SZ * NCHUNK * (DI / 64)), 256, 0, stream>>>(
      shared16, xcb, xdbl, A_log, xz);
  scan_phase3<<<dim3(B_SZ * NCHUNK * (DI / 64)), 256, 0, stream>>>(
      shared16, xcb, xdbl, A_log, Dskip, xz);
  // 8. GEMM4: out = y @ Wout (M=2048, N=1024, K=2048), direct write to d_out
  gemm_out<<<dim3(DM / 64, 2048 / 64), 256, 0, stream>>>(
      (ushortT*)xz, 4 * DI, WoutT, DI, (float*)d_out);
}